// Round 7
// baseline (720.420 us; speedup 1.0000x reference)
//
#include <hip/hip_runtime.h>
#include <hip/hip_bf16.h>

#define H 128
#define LATD 32

typedef __attribute__((ext_vector_type(8))) _Float16 half8t;        // 8 fp16
typedef __attribute__((ext_vector_type(4))) _Float16 half4t;        // 4 fp16
typedef __attribute__((ext_vector_type(2))) _Float16 half2t;        // 2 fp16
typedef __attribute__((ext_vector_type(8))) unsigned short u16x8;   // 16B copy unit
typedef __attribute__((ext_vector_type(4))) float f32x4;

// packed-weight region offsets (u16 elements)
#define OFF_RBF 0         // 3 x [1kt][8ct][64][8]   (We1 rows 256..271, zero-padded K=32)
#define OFF_W2  12288     // 3 x [4kt][8ct][64][8]   (We2)
#define OFF_PROJ 61440    // 3 x [4kt][16ct][64][8]  ([We1_src | We1_dst] 128x256)
#define OFF_H1  159744    // 3 x [8kt][8ct][64][8]   (Wh1)
#define OFF_H2  258048    // 3 x [4kt][8ct][64][8]   (Wh2)
#define OFF_KV  307200    // 1 x [4kt][16ct][64][8]  ([Wk | Wv] 128x256)
#define WP_TOTAL 339968

// silu via native rcp (avoids IEEE div sequence)
__device__ __forceinline__ float silu_f(float x) {
  return x * __builtin_amdgcn_rcpf(1.0f + __expf(-x));
}
__device__ __forceinline__ unsigned short f16u(float x) {
  _Float16 hh = (_Float16)x;
  return *(unsigned short*)&hh;
}

__global__ void k_init_h(const float* __restrict__ atom_embed,
                         const float* __restrict__ residue_embed,
                         const int* __restrict__ atype,
                         const int* __restrict__ ridx,
                         const int* __restrict__ rtype,
                         float* __restrict__ h, unsigned short* __restrict__ hb, int A) {
  int i = blockIdx.x * blockDim.x + threadIdx.x;
  if (i >= A * H) return;
  int a = i >> 7, j = i & 127;
  float v = atom_embed[atype[a] * H + j] + residue_embed[rtype[ridx[a]] * H + j];
  h[i] = v;
  hb[i] = f16u(v);
}

__global__ void k_dist(const float* __restrict__ coords,
                       const int* __restrict__ esrc, const int* __restrict__ edst,
                       float* __restrict__ dbuf, int E) {
  int e = blockIdx.x * blockDim.x + threadIdx.x;
  if (e >= E) return;
  int s = esrc[e], t = edst[e];
  float dx = coords[3*s+0] - coords[3*t+0];
  float dy = coords[3*s+1] - coords[3*t+1];
  float dz = coords[3*s+2] - coords[3*t+2];
  dbuf[e] = sqrtf(dx*dx + dy*dy + dz*dz);
}

__global__ void k_starts(const int* __restrict__ ridx, int* __restrict__ starts, int A) {
  int a = blockIdx.x * blockDim.x + threadIdx.x;
  if (a >= A) return;
  if (a == 0 || ridx[a] != ridx[a-1]) starts[ridx[a]] = a;
}

__global__ void k_bias2(const float* __restrict__ b1, const float* __restrict__ b2,
                        float* __restrict__ bkv) {
  int t = threadIdx.x;
  bkv[t] = (t < 128) ? b1[t] : b2[t - 128];
}

// ---------------- counting sort of edges by dst ----------------------------
__global__ void k_hist(const int* __restrict__ edst, int* __restrict__ cnt, int E) {
  int e = blockIdx.x * blockDim.x + threadIdx.x;
  if (e < E) atomicAdd(&cnt[edst[e]], 1);
}

__global__ __launch_bounds__(1024) void k_scanA(const int* __restrict__ cnt,
                                                int* __restrict__ cursor,
                                                int* __restrict__ bsum, int A) {
  __shared__ int buf[1024];
  int tid = threadIdx.x;
  int i = blockIdx.x * 1024 + tid;
  int v = (i < A) ? cnt[i] : 0;
  buf[tid] = v;
  __syncthreads();
  #pragma unroll
  for (int off = 1; off < 1024; off <<= 1) {
    int nv = (tid >= off) ? buf[tid - off] : 0;
    __syncthreads();
    buf[tid] += nv;
    __syncthreads();
  }
  if (i < A) cursor[i] = buf[tid] - v;   // exclusive within chunk
  if (tid == 1023) bsum[blockIdx.x] = buf[1023];
}

__global__ void k_scanB(int* __restrict__ bsum, int nb) {
  int lane = threadIdx.x;                 // one wave, nb <= 64
  int v = (lane < nb) ? bsum[lane] : 0;
  int s = v;
  #pragma unroll
  for (int off = 1; off < 64; off <<= 1) {
    int nv = __shfl_up(s, off);
    if (lane >= off) s += nv;
  }
  if (lane < nb) bsum[lane] = s - v;      // exclusive
}

__global__ void k_scanC(int* __restrict__ cursor, const int* __restrict__ bsum, int A) {
  int i = blockIdx.x * blockDim.x + threadIdx.x;
  if (i < A) cursor[i] += bsum[i >> 10];
}

__global__ void k_scatter(const int* __restrict__ edst, int* __restrict__ cursor,
                          int* __restrict__ eperm, int E) {
  int e = blockIdx.x * blockDim.x + threadIdx.x;
  if (e >= E) return;
  int p = atomicAdd(&cursor[edst[e]], 1);
  eperm[p] = e;
}

// ---------------- weight packing into per-lane-contiguous fragments --------
__global__ void k_pack(const float* __restrict__ We1, const float* __restrict__ We2,
                       const float* __restrict__ Wh1, const float* __restrict__ Wh2,
                       const float* __restrict__ Wk,  const float* __restrict__ Wv,
                       unsigned short* __restrict__ wp) {
  int t = blockIdx.x * blockDim.x + threadIdx.x;
  if (t >= WP_TOTAL) return;
  if (t < OFF_W2) {                      // rbf: We1 rows 256..271, K padded to 32
    int u = t - OFF_RBF; int layer = u / 4096, idx = u % 4096;
    int i = idx & 7, lane = (idx >> 3) & 63, ct = (idx >> 9) & 7;
    int k = ((lane >> 4) * 8) + i;
    int c = ct * 16 + (lane & 15);
    const float* src = We1 + (size_t)layer * 272 * H;
    wp[t] = f16u(k < 16 ? src[(size_t)(256 + k) * H + c] : 0.0f);
  } else if (t < OFF_PROJ) {             // We2 128x128
    int u = t - OFF_W2; int layer = u / 16384, idx = u % 16384;
    int i = idx & 7, lane = (idx >> 3) & 63, ct = (idx >> 9) & 7, kt = idx >> 12;
    int k = kt * 32 + (lane >> 4) * 8 + i, c = ct * 16 + (lane & 15);
    const float* src = We2 + (size_t)layer * 128 * H;
    wp[t] = f16u(src[(size_t)k * H + c]);
  } else if (t < OFF_H1) {               // proj: [We1_src | We1_dst] 128x256
    int u = t - OFF_PROJ; int layer = u / 32768, idx = u % 32768;
    int i = idx & 7, lane = (idx >> 3) & 63, ct = (idx >> 9) & 15, kt = idx >> 13;
    int k = kt * 32 + (lane >> 4) * 8 + i, c = ct * 16 + (lane & 15);
    const float* src = We1 + (size_t)layer * 272 * H;
    float v = (c < 128) ? src[(size_t)k * H + c] : src[(size_t)(128 + k) * H + (c - 128)];
    wp[t] = f16u(v);
  } else if (t < OFF_H2) {               // Wh1 256x128
    int u = t - OFF_H1; int layer = u / 32768, idx = u % 32768;
    int i = idx & 7, lane = (idx >> 3) & 63, ct = (idx >> 9) & 7, kt = idx >> 12;
    int k = kt * 32 + (lane >> 4) * 8 + i, c = ct * 16 + (lane & 15);
    const float* src = Wh1 + (size_t)layer * 256 * H;
    wp[t] = f16u(src[(size_t)k * H + c]);
  } else if (t < OFF_KV) {               // Wh2 128x128
    int u = t - OFF_H2; int layer = u / 16384, idx = u % 16384;
    int i = idx & 7, lane = (idx >> 3) & 63, ct = (idx >> 9) & 7, kt = idx >> 12;
    int k = kt * 32 + (lane >> 4) * 8 + i, c = ct * 16 + (lane & 15);
    const float* src = Wh2 + (size_t)layer * 128 * H;
    wp[t] = f16u(src[(size_t)k * H + c]);
  } else {                               // [Wk | Wv] 128x256
    int idx = t - OFF_KV;
    int i = idx & 7, lane = (idx >> 3) & 63, ct = (idx >> 9) & 15, kt = idx >> 13;
    int k = kt * 32 + (lane >> 4) * 8 + i, c = ct * 16 + (lane & 15);
    float v = (c < 128) ? Wk[(size_t)k * H + c] : Wv[(size_t)k * H + (c - 128)];
    wp[t] = f16u(v);
  }
}

// ---------------- dense projection: out = hb @ Wp (+bias), out A x 256 fp16 -
__global__ __launch_bounds__(256) void k_proj(
    const unsigned short* __restrict__ hb, const unsigned short* __restrict__ Wp,
    unsigned short* __restrict__ Ph, int A, const float* __restrict__ bias) {
  const int tid = threadIdx.x, l = tid & 63, wv = tid >> 6;
  const int lr = l & 15, lk = (l >> 4) * 8;
  const int a0 = blockIdx.x * 64;
  f32x4 acc[4][4] = {};
  #pragma unroll
  for (int kt = 0; kt < 4; ++kt) {
    half8t a[4], b[4];
    #pragma unroll
    for (int rt = 0; rt < 4; ++rt) {
      int row = a0 + rt * 16 + lr; if (row >= A) row = A - 1;
      a[rt] = *(const half8t*)&hb[(size_t)row * H + kt * 32 + lk];
    }
    #pragma unroll
    for (int ci = 0; ci < 4; ++ci)
      b[ci] = *(const half8t*)&Wp[(((size_t)kt * 16 + wv * 4 + ci) * 64 + l) * 8];
    #pragma unroll
    for (int rt = 0; rt < 4; ++rt)
      #pragma unroll
      for (int ci = 0; ci < 4; ++ci)
        acc[rt][ci] = __builtin_amdgcn_mfma_f32_16x16x32_f16(a[rt], b[ci], acc[rt][ci], 0, 0, 0);
  }
  #pragma unroll
  for (int rt = 0; rt < 4; ++rt)
    #pragma unroll
    for (int ci = 0; ci < 4; ++ci) {
      int col = (wv * 4 + ci) * 16 + lr;
      float bb = bias ? bias[col] : 0.0f;
      #pragma unroll
      for (int rr = 0; rr < 4; ++rr) {
        int row = a0 + rt * 16 + (l >> 4) * 4 + rr;
        if (row < A) Ph[(size_t)row * 256 + col] = f16u(acc[rt][ci][rr] + bb);
      }
    }
}

// ---------------- edge kernel: direct-gather + in-reg rbf + fp16 M2 --------
// 64 dst-sorted edges / block, 256 threads (4 waves). LDS = M1 only (17.7KB).
#define M1S 136   // M1 stride (fp16)
#define M2SH 132  // M2 fp16 stride (aliases M1 region)

__global__ __launch_bounds__(256) void k_edge_mfma(
    const unsigned short* __restrict__ Ph, const float* __restrict__ dbuf,
    const int* __restrict__ esrc, const int* __restrict__ edst,
    const int* __restrict__ eperm,
    const unsigned short* __restrict__ Wr, const float* __restrict__ be1,
    const unsigned short* __restrict__ W2p, const float* __restrict__ be2,
    float* __restrict__ agg, int E) {
  __shared__ __align__(16) unsigned short M1s[64 * M1S];  // 17408 B
  __shared__ int dstv[64];
  unsigned short* M2h = M1s;   // fp16 M2 aliases M1 (dead after mm2 barrier)

  const int tid = threadIdx.x;
  const int e0 = blockIdx.x * 64;
  const int l = tid & 63, wv = tid >> 6;
  const int lr = l & 15, lk = (l >> 4) * 8, g4 = (l >> 4) * 4;
  const int ct0 = wv * 2;

  // per-row metadata for my 4 rows (row = et*16 + lr)
  int sA[4], tA[4];
  float dA[4];
  #pragma unroll
  for (int et = 0; et < 4; ++et) {
    int e = e0 + et * 16 + lr;
    int ec = (e < E) ? e : (E - 1);
    int es = eperm[ec];
    sA[et] = esrc[es];
    tA[et] = edst[es];
    dA[et] = dbuf[es];
  }
  if (tid < 64) {
    int e = e0 + tid;
    int ec = (e < E) ? e : (E - 1);
    dstv[tid] = (e < E) ? edst[eperm[ec]] : -1;
  }

  // ---- mm1T: acc = (Ph_src + Ph_dst)^T direct gather + Wr^T @ rbf^T ----
  f32x4 acc[2][4];
  #pragma unroll
  for (int cj = 0; cj < 2; ++cj) {
    int cbase = (ct0 + cj) * 16 + g4;
    #pragma unroll
    for (int et = 0; et < 4; ++et) {
      half4t a = *(const half4t*)&Ph[(size_t)sA[et] * 256 + cbase];
      half4t b = *(const half4t*)&Ph[(size_t)tA[et] * 256 + 128 + cbase];
      half4t p = a + b;              // v_pk_add_f16
      acc[cj][et][0] = (float)p[0];
      acc[cj][et][1] = (float)p[1];
      acc[cj][et][2] = (float)p[2];
      acc[cj][et][3] = (float)p[3];
    }
  }
  {
    // rbf fragments in-register: br[et][i] = rbf_j(d), j = lk+i (0 for j>=16)
    half8t br[4];
    if (lk < 16) {
      #pragma unroll
      for (int et = 0; et < 4; ++et) {
        float d = dA[et];
        #pragma unroll
        for (int i = 0; i < 8; ++i) {
          float dd = d - (float)(lk + i) * (5.0f / 15.0f);
          br[et][i] = (_Float16)__expf(-10.24f * dd * dd);
        }
      }
    } else {
      #pragma unroll
      for (int et = 0; et < 4; ++et)
        #pragma unroll
        for (int i = 0; i < 8; ++i) br[et][i] = (_Float16)0.0f;
    }
    half8t ar[2];
    #pragma unroll
    for (int cj = 0; cj < 2; ++cj)
      ar[cj] = *(const half8t*)&Wr[(((size_t)(ct0 + cj)) * 64 + l) * 8];
    #pragma unroll
    for (int et = 0; et < 4; ++et)
      #pragma unroll
      for (int cj = 0; cj < 2; ++cj)
        acc[cj][et] = __builtin_amdgcn_mfma_f32_16x16x32_f16(ar[cj], br[et], acc[cj][et], 0, 0, 0);
  }
  // silu(acc + be1) -> M1[e][c] as packed b64
  #pragma unroll
  for (int cj = 0; cj < 2; ++cj) {
    f32x4 b1v = *(const f32x4*)&be1[(ct0 + cj) * 16 + g4];
    #pragma unroll
    for (int et = 0; et < 4; ++et) {
      half4t m4;
      #pragma unroll
      for (int rr = 0; rr < 4; ++rr)
        m4[rr] = (_Float16)silu_f(acc[cj][et][rr] + b1v[rr]);
      *(half4t*)&M1s[(et * 16 + lr) * M1S + (ct0 + cj) * 16 + g4] = m4;
    }
  }
  __syncthreads();

  // ---- mm2T: acc2 = We2^T @ M1^T ----
  f32x4 acc2[2][4] = {};
  #pragma unroll
  for (int kt = 0; kt < 4; ++kt) {
    half8t a2[2], b2[4];
    #pragma unroll
    for (int cj = 0; cj < 2; ++cj)
      a2[cj] = *(const half8t*)&W2p[(((size_t)kt * 8 + ct0 + cj) * 64 + l) * 8];
    #pragma unroll
    for (int et = 0; et < 4; ++et)
      b2[et] = *(const half8t*)&M1s[(et * 16 + lr) * M1S + kt * 32 + lk];
    #pragma unroll
    for (int cj = 0; cj < 2; ++cj)
      #pragma unroll
      for (int et = 0; et < 4; ++et)
        acc2[cj][et] = __builtin_amdgcn_mfma_f32_16x16x32_f16(a2[cj], b2[et], acc2[cj][et], 0, 0, 0);
  }
  __syncthreads();   // M1 reads done -> safe to alias-write M2h
  #pragma unroll
  for (int cj = 0; cj < 2; ++cj) {
    f32x4 b2v = *(const f32x4*)&be2[(ct0 + cj) * 16 + g4];
    #pragma unroll
    for (int et = 0; et < 4; ++et) {
      half4t m4;
      #pragma unroll
      for (int rr = 0; rr < 4; ++rr)
        m4[rr] = (_Float16)silu_f(acc2[cj][et][rr] + b2v[rr]);
      *(half4t*)&M2h[(et * 16 + lr) * M2SH + (ct0 + cj) * 16 + g4] = m4;
    }
  }
  __syncthreads();

  // ---- segmented reduce over dst runs: thread = (colpair, row-quarter) ----
  {
    int cp = tid & 63, qr = tid >> 6;
    int rbeg = qr * 16, rend = rbeg + 16;
    float a0 = 0.f, a1 = 0.f;
    int prev = -1;
    for (int r = rbeg; r < rend; ++r) {
      int dv = dstv[r];
      half2t v = *(const half2t*)&M2h[r * M2SH + cp * 2];
      if (dv != prev) {
        if (prev >= 0) {
          atomicAdd(&agg[(size_t)prev * H + cp * 2], a0);
          atomicAdd(&agg[(size_t)prev * H + cp * 2 + 1], a1);
        }
        a0 = a1 = 0.f;
        prev = dv;
      }
      if (dv >= 0) { a0 += (float)v[0]; a1 += (float)v[1]; }
    }
    if (prev >= 0) {
      atomicAdd(&agg[(size_t)prev * H + cp * 2], a0);
      atomicAdd(&agg[(size_t)prev * H + cp * 2 + 1], a1);
    }
  }
}

// ---------------- node MLP: fp16 MFMA, 32 atoms/block ----------------------
#define NXS 264   // X stride fp16 (528B)

__global__ __launch_bounds__(256) void k_node_mfma(
    float* __restrict__ h, unsigned short* __restrict__ hb,
    const float* __restrict__ agg,
    const unsigned short* __restrict__ W1p, const float* __restrict__ bh1,
    const unsigned short* __restrict__ W2p, const float* __restrict__ bh2, int A) {
  __shared__ __align__(16) unsigned short Xs[32 * NXS];   // 16896 B
  __shared__ __align__(16) unsigned short Us[32 * M1S];   //  8704 B
  const int tid = threadIdx.x;
  const int a0 = blockIdx.x * 32;
  {
    const int r = tid >> 3, oct = tid & 7;   // 8 threads per atom row
    int a = a0 + r; if (a >= A) a = A - 1;
    const u16x8* hr = (const u16x8*)(hb + (size_t)a * H);
    u16x8* xr = (u16x8*)&Xs[r * NXS];
    xr[oct * 2]     = hr[oct * 2];
    xr[oct * 2 + 1] = hr[oct * 2 + 1];
    const float4* ar = (const float4*)(agg + (size_t)a * H);
    u16x8 tmp[2];
    unsigned short* tp = (unsigned short*)tmp;
    #pragma unroll
    for (int i = 0; i < 4; ++i) {
      float4 av = ar[oct * 4 + i];
      tp[i*4+0] = f16u(av.x); tp[i*4+1] = f16u(av.y);
      tp[i*4+2] = f16u(av.z); tp[i*4+3] = f16u(av.w);
    }
    xr[16 + oct * 2]     = tmp[0];
    xr[16 + oct * 2 + 1] = tmp[1];
  }
  __syncthreads();

  const int l = tid & 63, wv = tid >> 6;
  const int lr = l & 15, lk = (l >> 4) * 8;
  const int ct0 = wv * 2;
  const int c0 = ct0 * 16 + lr, c1 = c0 + 16;
  const float b1a = bh1[c0], b1b = bh1[c1];
  const float b2a = bh2[c0], b2b = bh2[c1];

  f32x4 acc[2][2] = {};
  #pragma unroll
  for (int kt = 0; kt < 8; ++kt) {
    half8t a[2], b[2];
    #pragma unroll
    for (int rt = 0; rt < 2; ++rt)
      a[rt] = *(const half8t*)&Xs[(rt * 16 + lr) * NXS + kt * 32 + lk];
    #pragma unroll
    for (int j = 0; j < 2; ++j)
      b[j] = *(const half8t*)&W1p[(((size_t)kt * 8 + ct0 + j) * 64 + l) * 8];
    #pragma unroll
    for (int rt = 0; rt < 2; ++rt)
      #pragma unroll
      for (int j = 0; j < 2; ++j)
        acc[rt][j] = __builtin_amdgcn_mfma_f32_16x16x32_f16(a[rt], b[j], acc[rt][j], 0, 0, 0);
  }
  #pragma unroll
  for (int rt = 0; rt < 2; ++rt)
    #pragma unroll
    for (int j = 0; j < 2; ++j) {
      float bb = j ? b1b : b1a;
      int col = (ct0 + j) * 16 + lr;
      #pragma unroll
      for (int rr = 0; rr < 4; ++rr) {
        int row = rt * 16 + (l >> 4) * 4 + rr;
        Us[row * M1S + col] = f16u(silu_f(acc[rt][j][rr] + bb));
      }
    }
  __syncthreads();

  f32x4 acc2[2][2] = {};
  #pragma unroll
  for (int kt = 0; kt < 4; ++kt) {
    half8t a[2], b[2];
    #pragma unroll
    for (int rt = 0; rt < 2; ++rt)
      a[rt] = *(const half8t*)&Us[(rt * 16 + lr) * M1S + kt * 32 + lk];
    #pragma unroll
    for (int j = 0; j < 2; ++j)
      b[j] = *(const half8t*)&W2p[(((size_t)kt * 8 + ct0 + j) * 64 + l) * 8];
    #pragma unroll
    for (int rt = 0; rt < 2; ++rt)
      #pragma unroll
      for (int j = 0; j < 2; ++j)
        acc2[rt][j] = __builtin_amdgcn_mfma_f32_16x16x32_f16(a[rt], b[j], acc2[rt][j], 0, 0, 0);
  }
  #pragma unroll
  for (int rt = 0; rt < 2; ++rt)
    #pragma unroll
    for (int j = 0; j < 2; ++j) {
      float bb = j ? b2b : b2a;
      int col = (ct0 + j) * 16 + lr;
      #pragma unroll
      for (int rr = 0; rr < 4; ++rr) {
        int row = rt * 16 + (l >> 4) * 4 + rr;
        int a = a0 + row;
        if (a < A) {
          size_t off = (size_t)a * H + col;
          float nh = h[off] + acc2[rt][j][rr] + bb;
          h[off] = nh;
          hb[off] = f16u(nh);
        }
      }
    }
}

// ---------------- tail kernels ---------------------------------------------
// q4 = residue_embed[0..3] @ Wq + bq  (only 4 distinct residue types)
__global__ void k_q4(const float* __restrict__ residue_embed,
                     const float* __restrict__ Wq, const float* __restrict__ bq,
                     float* __restrict__ q4) {
  int i = blockIdx.x * blockDim.x + threadIdx.x;
  if (i >= 4 * H) return;
  int r = i >> 7, j = i & 127;
  const float* emb = residue_embed + (size_t)r * H;
  float s = bq[j];
  #pragma unroll 4
  for (int k = 0; k < H; ++k) s += emb[k] * Wq[(size_t)k*H + j];
  q4[i] = s;
}

// per-residue attention pooling over fp16 kv rows [k(128) | v(128)]
__global__ __launch_bounds__(256) void k_pool(
    const float* __restrict__ q4, const int* __restrict__ rtype,
    const unsigned short* __restrict__ kv, const int* __restrict__ starts,
    const int* __restrict__ apr, float* __restrict__ pooled, int N) {
  int r = blockIdx.x * 4 + (threadIdx.x >> 6);
  if (r >= N) return;
  int lane = threadIdx.x & 63;
  int s0 = starts[r], cnt = apr[r];
  const float* qrow = q4 + (size_t)rtype[r] * H;
  float q0 = qrow[lane], q1 = qrow[64 + lane];
  float myscore = -1e30f;
  for (int i = 0; i < cnt; ++i) {
    const unsigned short* kr = kv + (size_t)(s0 + i) * 256;
    float p = q0 * (float)(*(const _Float16*)&kr[lane]) +
              q1 * (float)(*(const _Float16*)&kr[64 + lane]);
    #pragma unroll
    for (int off = 32; off; off >>= 1) p += __shfl_xor(p, off);
    if (lane == i) myscore = p * 0.08838834764831845f;
  }
  float val = (lane < cnt) ? myscore : -1e30f;
  float mx = val;
  #pragma unroll
  for (int off = 32; off; off >>= 1) mx = fmaxf(mx, __shfl_xor(mx, off));
  float ex = (lane < cnt) ? __expf(val - mx) : 0.0f;
  float sum = ex;
  #pragma unroll
  for (int off = 32; off; off >>= 1) sum += __shfl_xor(sum, off);
  float w = ex * __builtin_amdgcn_rcpf(sum);
  float p0 = 0.f, p1 = 0.f;
  for (int i = 0; i < cnt; ++i) {
    float wi = __shfl(w, i);
    const unsigned short* vr = kv + (size_t)(s0 + i) * 256 + 128;
    p0 += wi * (float)(*(const _Float16*)&vr[lane]);
    p1 += wi * (float)(*(const _Float16*)&vr[64 + lane]);
  }
  pooled[(size_t)r*H + lane] = p0;
  pooled[(size_t)r*H + 64 + lane] = p1;
}

__global__ void k_head(const float* __restrict__ pooled,
                       const float* __restrict__ Wmu, const float* __restrict__ bmu,
                       const float* __restrict__ Wlv, const float* __restrict__ blv,
                       float* __restrict__ out, int N) {
  int i = blockIdx.x * blockDim.x + threadIdx.x;
  if (i >= N * LATD) return;
  int r = i >> 5, j = i & 31;
  const float* p = pooled + (size_t)r * H;
  float smu = 0.f, slv = 0.f;
  #pragma unroll 4
  for (int k = 0; k < H; ++k) {
    float pv = p[k];
    smu += pv * Wmu[(size_t)k*LATD + j];
    slv += pv * Wlv[(size_t)k*LATD + j];
  }
  smu += bmu[j];
  slv += blv[j];
  slv = fminf(fmaxf(slv, -10.0f), 2.0f);
  out[i] = smu;
  out[(size_t)N*LATD + i] = slv;
}

extern "C" void kernel_launch(void* const* d_in, const int* in_sizes, int n_in,
                              void* d_out, int out_size, void* d_ws, size_t ws_size,
                              hipStream_t stream) {
  const float* coords        = (const float*)d_in[0];
  const int*   atype         = (const int*)d_in[1];
  const int*   ridx          = (const int*)d_in[2];
  const int*   rtype         = (const int*)d_in[3];
  const int*   apr           = (const int*)d_in[4];
  const int*   esrc          = (const int*)d_in[5];
  const int*   edst          = (const int*)d_in[6];
  const float* atom_embed    = (const float*)d_in[7];
  const float* residue_embed = (const float*)d_in[8];
  const float* We1 = (const float*)d_in[9];
  const float* be1 = (const float*)d_in[10];
  const float* We2 = (const float*)d_in[11];
  const float* be2 = (const float*)d_in[12];
  const float* Wh1 = (const float*)d_in[13];
  const float* bh1 = (const float*)d_in[14];
  const float* Wh2 = (const float*)d_in[15];
  const float* bh2 = (const float*)d_in[16];
  const float* Wq  = (const float*)d_in[17];
  const float* bq  = (const float*)d_in[18];
  const float* Wk  = (const float*)d_in[19];
  const float* bk  = (const float*)d_in[20];
  const float* Wv  = (const float*)d_in[21];
  const float* bv  = (const float*)d_in[22];
  const float* Wmu = (const float*)d_in[23];
  const float* bmu = (const float*)d_in[24];
  const float* Wlv = (const float*)d_in[25];
  const float* blv = (const float*)d_in[26];

  const int A = in_sizes[1];
  const int N = in_sizes[3];
  const int E = in_sizes[5];

  float* ws     = (float*)d_ws;
  float* h      = ws;                              // A*H f32
  float* agg    = h + (size_t)A * H;               // A*H f32
  float* vbuf   = agg + (size_t)A * H;             // A*H f32 (aliased: Ph, then kv)
  float* dbuf   = vbuf + (size_t)A * H;            // E f32
  float* q4     = dbuf + (size_t)E;                // 4*H
  float* bkv    = q4 + 4 * H;                      // 256
  float* pooled = bkv + 256;                       // N*H
  int*   starts = (int*)(pooled + (size_t)N * H);  // N
  unsigned short* hbuf = (unsigned short*)(starts + N);  // A*H fp16
  int*   eperm  = (int*)(hbuf + (size_t)A * H);    // E
  int*   cnt    = eperm + (size_t)E;               // A
  int*   cursor = cnt + A;                         // A
  int*   bsum   = cursor + A;                      // 64
  unsigned short* wp = (unsigned short*)(bsum + 64);     // WP_TOTAL fp16
  unsigned short* Ph = (unsigned short*)vbuf;      // A*256 fp16 == A*H f32 bytes

  k_init_h<<<(A * H + 255) / 256, 256, 0, stream>>>(atom_embed, residue_embed,
                                                    atype, ridx, rtype, h, hbuf, A);
  k_dist<<<(E + 255) / 256, 256, 0, stream>>>(coords, esrc, edst, dbuf, E);
  k_starts<<<(A + 255) / 256, 256, 0, stream>>>(ridx, starts, A);
  k_pack<<<(WP_TOTAL + 255) / 256, 256, 0, stream>>>(We1, We2, Wh1, Wh2, Wk, Wv, wp);
  k_bias2<<<1, 256, 0, stream>>>(bk, bv, bkv);

  // counting sort of edges by dst (two-level scan)
  const int nb = (A + 1023) / 1024;
  hipMemsetAsync(cnt, 0, (size_t)A * sizeof(int), stream);
  k_hist<<<(E + 255) / 256, 256, 0, stream>>>(edst, cnt, E);
  k_scanA<<<nb, 1024, 0, stream>>>(cnt, cursor, bsum, A);
  k_scanB<<<1, 64, 0, stream>>>(bsum, nb);
  k_scanC<<<(A + 255) / 256, 256, 0, stream>>>(cursor, bsum, A);
  k_scatter<<<(E + 255) / 256, 256, 0, stream>>>(edst, cursor, eperm, E);

  for (int l = 0; l < 3; ++l) {
    hipMemsetAsync(agg, 0, (size_t)A * H * sizeof(float), stream);
    k_proj<<<(A + 63) / 64, 256, 0, stream>>>(
        hbuf, wp + OFF_PROJ + (size_t)l * 32768, Ph, A, nullptr);
    k_edge_mfma<<<(E + 63) / 64, 256, 0, stream>>>(
        Ph, dbuf, esrc, edst, eperm,
        wp + OFF_RBF + (size_t)l * 4096,  be1 + (size_t)l * H,
        wp + OFF_W2  + (size_t)l * 16384, be2 + (size_t)l * H, agg, E);
    k_node_mfma<<<(A + 31) / 32, 256, 0, stream>>>(
        h, hbuf, agg,
        wp + OFF_H1 + (size_t)l * 32768, bh1 + (size_t)l * H,
        wp + OFF_H2 + (size_t)l * 16384, bh2 + (size_t)l * H, A);
  }

  k_q4<<<2, 256, 0, stream>>>(residue_embed, Wq, bq, q4);
  unsigned short* kv = Ph;  // Ph dead after last edge; reuse A*256 fp16 region
  k_proj<<<(A + 63) / 64, 256, 0, stream>>>(hbuf, wp + OFF_KV, kv, A, bkv);
  k_pool<<<(N + 3) / 4, 256, 0, stream>>>(q4, rtype, kv, starts, apr, pooled, N);
  k_head<<<(N * LATD + 255) / 256, 256, 0, stream>>>(pooled, Wmu, bmu, Wlv, blv,
                                                     (float*)d_out, N);
}

// Round 8
// 638.863 us; speedup vs baseline: 1.1277x; 1.1277x over previous
//
#include <hip/hip_runtime.h>
#include <hip/hip_bf16.h>

#define H 128
#define LATD 32

typedef __attribute__((ext_vector_type(8))) _Float16 half8t;        // 8 fp16
typedef __attribute__((ext_vector_type(4))) _Float16 half4t;        // 4 fp16
typedef __attribute__((ext_vector_type(2))) _Float16 half2t;        // 2 fp16
typedef __attribute__((ext_vector_type(8))) unsigned short u16x8;   // 16B copy unit
typedef __attribute__((ext_vector_type(4))) float f32x4;

// packed-weight region offsets (u16 elements)
#define OFF_RBF 0         // 3 x [1kt][8ct][64][8]   (We1 rows 256..271, zero-padded K=32)
#define OFF_W2  12288     // 3 x [4kt][8ct][64][8]   (We2)
#define OFF_PROJ 61440    // 3 x [4kt][16ct][64][8]  ([We1_src | We1_dst] 128x256)
#define OFF_H1  159744    // 3 x [8kt][8ct][64][8]   (Wh1)
#define OFF_H2  258048    // 3 x [4kt][8ct][64][8]   (Wh2)
#define OFF_KV  307200    // 1 x [4kt][16ct][64][8]  ([Wk | Wv] 128x256)
#define WP_TOTAL 339968

// silu via native rcp (avoids IEEE div sequence)
__device__ __forceinline__ float silu_f(float x) {
  return x * __builtin_amdgcn_rcpf(1.0f + __expf(-x));
}
__device__ __forceinline__ unsigned short f16u(float x) {
  _Float16 hh = (_Float16)x;
  return *(unsigned short*)&hh;
}

__global__ void k_init_h(const float* __restrict__ atom_embed,
                         const float* __restrict__ residue_embed,
                         const int* __restrict__ atype,
                         const int* __restrict__ ridx,
                         const int* __restrict__ rtype,
                         float* __restrict__ h, unsigned short* __restrict__ hb, int A) {
  int i = blockIdx.x * blockDim.x + threadIdx.x;
  if (i >= A * H) return;
  int a = i >> 7, j = i & 127;
  float v = atom_embed[atype[a] * H + j] + residue_embed[rtype[ridx[a]] * H + j];
  h[i] = v;
  hb[i] = f16u(v);
}

__global__ void k_dist(const float* __restrict__ coords,
                       const int* __restrict__ esrc, const int* __restrict__ edst,
                       float* __restrict__ dbuf, int E) {
  int e = blockIdx.x * blockDim.x + threadIdx.x;
  if (e >= E) return;
  int s = esrc[e], t = edst[e];
  float dx = coords[3*s+0] - coords[3*t+0];
  float dy = coords[3*s+1] - coords[3*t+1];
  float dz = coords[3*s+2] - coords[3*t+2];
  dbuf[e] = sqrtf(dx*dx + dy*dy + dz*dz);
}

__global__ void k_starts(const int* __restrict__ ridx, int* __restrict__ starts, int A) {
  int a = blockIdx.x * blockDim.x + threadIdx.x;
  if (a >= A) return;
  if (a == 0 || ridx[a] != ridx[a-1]) starts[ridx[a]] = a;
}

__global__ void k_bias2(const float* __restrict__ b1, const float* __restrict__ b2,
                        float* __restrict__ bkv) {
  int t = threadIdx.x;
  bkv[t] = (t < 128) ? b1[t] : b2[t - 128];
}

// ---------------- counting sort of edges by dst ----------------------------
__global__ void k_hist(const int* __restrict__ edst, int* __restrict__ cnt, int E) {
  int e = blockIdx.x * blockDim.x + threadIdx.x;
  if (e < E) atomicAdd(&cnt[edst[e]], 1);
}

__global__ __launch_bounds__(1024) void k_scanA(const int* __restrict__ cnt,
                                                int* __restrict__ cursor,
                                                int* __restrict__ bsum, int A) {
  __shared__ int buf[1024];
  int tid = threadIdx.x;
  int i = blockIdx.x * 1024 + tid;
  int v = (i < A) ? cnt[i] : 0;
  buf[tid] = v;
  __syncthreads();
  #pragma unroll
  for (int off = 1; off < 1024; off <<= 1) {
    int nv = (tid >= off) ? buf[tid - off] : 0;
    __syncthreads();
    buf[tid] += nv;
    __syncthreads();
  }
  if (i < A) cursor[i] = buf[tid] - v;   // exclusive within chunk
  if (tid == 1023) bsum[blockIdx.x] = buf[1023];
}

__global__ void k_scanB(int* __restrict__ bsum, int nb) {
  int lane = threadIdx.x;                 // one wave, nb <= 64
  int v = (lane < nb) ? bsum[lane] : 0;
  int s = v;
  #pragma unroll
  for (int off = 1; off < 64; off <<= 1) {
    int nv = __shfl_up(s, off);
    if (lane >= off) s += nv;
  }
  if (lane < nb) bsum[lane] = s - v;      // exclusive
}

__global__ void k_scanC(int* __restrict__ cursor, const int* __restrict__ bsum, int A) {
  int i = blockIdx.x * blockDim.x + threadIdx.x;
  if (i < A) cursor[i] += bsum[i >> 10];
}

__global__ void k_scatter(const int* __restrict__ edst, int* __restrict__ cursor,
                          int* __restrict__ eperm, int E) {
  int e = blockIdx.x * blockDim.x + threadIdx.x;
  if (e >= E) return;
  int p = atomicAdd(&cursor[edst[e]], 1);
  eperm[p] = e;
}

// ---------------- weight packing into per-lane-contiguous fragments --------
__global__ void k_pack(const float* __restrict__ We1, const float* __restrict__ We2,
                       const float* __restrict__ Wh1, const float* __restrict__ Wh2,
                       const float* __restrict__ Wk,  const float* __restrict__ Wv,
                       unsigned short* __restrict__ wp) {
  int t = blockIdx.x * blockDim.x + threadIdx.x;
  if (t >= WP_TOTAL) return;
  if (t < OFF_W2) {                      // rbf: We1 rows 256..271, K padded to 32
    int u = t - OFF_RBF; int layer = u / 4096, idx = u % 4096;
    int i = idx & 7, lane = (idx >> 3) & 63, ct = (idx >> 9) & 7;
    int k = ((lane >> 4) * 8) + i;
    int c = ct * 16 + (lane & 15);
    const float* src = We1 + (size_t)layer * 272 * H;
    wp[t] = f16u(k < 16 ? src[(size_t)(256 + k) * H + c] : 0.0f);
  } else if (t < OFF_PROJ) {             // We2 128x128
    int u = t - OFF_W2; int layer = u / 16384, idx = u % 16384;
    int i = idx & 7, lane = (idx >> 3) & 63, ct = (idx >> 9) & 7, kt = idx >> 12;
    int k = kt * 32 + (lane >> 4) * 8 + i, c = ct * 16 + (lane & 15);
    const float* src = We2 + (size_t)layer * 128 * H;
    wp[t] = f16u(src[(size_t)k * H + c]);
  } else if (t < OFF_H1) {               // proj: [We1_src | We1_dst] 128x256
    int u = t - OFF_PROJ; int layer = u / 32768, idx = u % 32768;
    int i = idx & 7, lane = (idx >> 3) & 63, ct = (idx >> 9) & 15, kt = idx >> 13;
    int k = kt * 32 + (lane >> 4) * 8 + i, c = ct * 16 + (lane & 15);
    const float* src = We1 + (size_t)layer * 272 * H;
    float v = (c < 128) ? src[(size_t)k * H + c] : src[(size_t)(128 + k) * H + (c - 128)];
    wp[t] = f16u(v);
  } else if (t < OFF_H2) {               // Wh1 256x128
    int u = t - OFF_H1; int layer = u / 32768, idx = u % 32768;
    int i = idx & 7, lane = (idx >> 3) & 63, ct = (idx >> 9) & 7, kt = idx >> 12;
    int k = kt * 32 + (lane >> 4) * 8 + i, c = ct * 16 + (lane & 15);
    const float* src = Wh1 + (size_t)layer * 256 * H;
    wp[t] = f16u(src[(size_t)k * H + c]);
  } else if (t < OFF_KV) {               // Wh2 128x128
    int u = t - OFF_H2; int layer = u / 16384, idx = u % 16384;
    int i = idx & 7, lane = (idx >> 3) & 63, ct = (idx >> 9) & 7, kt = idx >> 12;
    int k = kt * 32 + (lane >> 4) * 8 + i, c = ct * 16 + (lane & 15);
    const float* src = Wh2 + (size_t)layer * 128 * H;
    wp[t] = f16u(src[(size_t)k * H + c]);
  } else {                               // [Wk | Wv] 128x256
    int idx = t - OFF_KV;
    int i = idx & 7, lane = (idx >> 3) & 63, ct = (idx >> 9) & 15, kt = idx >> 13;
    int k = kt * 32 + (lane >> 4) * 8 + i, c = ct * 16 + (lane & 15);
    float v = (c < 128) ? Wk[(size_t)k * H + c] : Wv[(size_t)k * H + (c - 128)];
    wp[t] = f16u(v);
  }
}

// ---------------- dense projection: out = hb @ Wp (+bias), out A x 256 fp16 -
__global__ __launch_bounds__(256) void k_proj(
    const unsigned short* __restrict__ hb, const unsigned short* __restrict__ Wp,
    unsigned short* __restrict__ Ph, int A, const float* __restrict__ bias) {
  const int tid = threadIdx.x, l = tid & 63, wv = tid >> 6;
  const int lr = l & 15, lk = (l >> 4) * 8;
  const int a0 = blockIdx.x * 64;
  f32x4 acc[4][4] = {};
  #pragma unroll
  for (int kt = 0; kt < 4; ++kt) {
    half8t a[4], b[4];
    #pragma unroll
    for (int rt = 0; rt < 4; ++rt) {
      int row = a0 + rt * 16 + lr; if (row >= A) row = A - 1;
      a[rt] = *(const half8t*)&hb[(size_t)row * H + kt * 32 + lk];
    }
    #pragma unroll
    for (int ci = 0; ci < 4; ++ci)
      b[ci] = *(const half8t*)&Wp[(((size_t)kt * 16 + wv * 4 + ci) * 64 + l) * 8];
    #pragma unroll
    for (int rt = 0; rt < 4; ++rt)
      #pragma unroll
      for (int ci = 0; ci < 4; ++ci)
        acc[rt][ci] = __builtin_amdgcn_mfma_f32_16x16x32_f16(a[rt], b[ci], acc[rt][ci], 0, 0, 0);
  }
  #pragma unroll
  for (int rt = 0; rt < 4; ++rt)
    #pragma unroll
    for (int ci = 0; ci < 4; ++ci) {
      int col = (wv * 4 + ci) * 16 + lr;
      float bb = bias ? bias[col] : 0.0f;
      #pragma unroll
      for (int rr = 0; rr < 4; ++rr) {
        int row = a0 + rt * 16 + (l >> 4) * 4 + rr;
        if (row < A) Ph[(size_t)row * 256 + col] = f16u(acc[rt][ci][rr] + bb);
      }
    }
}

// ---------------- edge kernel: staged gather + single aliased LDS buffer ---
// 64 dst-sorted edges / block, 256 threads (4 waves).
// ONE 17.4KB buffer serves Psum -> M1 -> M2h phases (barrier-separated).
#define ES 136    // shared stride (fp16): 272B/row, 16B-aligned

__global__ __launch_bounds__(256) void k_edge_mfma(
    const unsigned short* __restrict__ Ph, const float* __restrict__ dbuf,
    const int* __restrict__ esrc, const int* __restrict__ edst,
    const int* __restrict__ eperm,
    const unsigned short* __restrict__ Wr, const float* __restrict__ be1,
    const unsigned short* __restrict__ W2p, const float* __restrict__ be2,
    float* __restrict__ agg, int E) {
  __shared__ __align__(16) unsigned short SH[64 * ES];  // 17408 B (Psum/M1/M2h)
  __shared__ int dstv[64];
  __shared__ float dval[64];

  const int tid = threadIdx.x;
  const int e0 = blockIdx.x * 64;
  const int l = tid & 63, wv = tid >> 6;
  const int lr = l & 15, lk = (l >> 4) * 8, g4 = (l >> 4) * 4;
  const int ct0 = wv * 2;

  // ---- phase 1: stage Psum (coalesced 16B gathers), d + dst to LDS ----
  {
    const int r = tid >> 2, qt = tid & 3;
    int e = e0 + r;
    int ec = (e < E) ? e : (E - 1);
    int es = eperm[ec];
    int s = esrc[es], t = edst[es];
    if (qt == 0) {
      dstv[r] = (e < E) ? t : -1;
      dval[r] = dbuf[es];
    }
    const half8t* ps = (const half8t*)(Ph + (size_t)s * 256);        // src proj
    const half8t* pt = (const half8t*)(Ph + (size_t)t * 256 + 128);  // dst proj
    half8t* pr = (half8t*)&SH[r * ES];
    #pragma unroll
    for (int i = 0; i < 4; ++i)
      pr[qt * 4 + i] = ps[qt * 4 + i] + pt[qt * 4 + i];   // v_pk_add_f16
  }
  __syncthreads();

  // ---- phase 2: acc init from Psum slivers + in-reg rbf MFMA ----
  f32x4 acc[2][4];
  #pragma unroll
  for (int cj = 0; cj < 2; ++cj) {
    int cbase = (ct0 + cj) * 16 + g4;
    #pragma unroll
    for (int et = 0; et < 4; ++et) {
      half4t p4 = *(const half4t*)&SH[(et * 16 + lr) * ES + cbase];
      acc[cj][et][0] = (float)p4[0];
      acc[cj][et][1] = (float)p4[1];
      acc[cj][et][2] = (float)p4[2];
      acc[cj][et][3] = (float)p4[3];
    }
  }
  {
    float dA[4];
    #pragma unroll
    for (int et = 0; et < 4; ++et) dA[et] = dval[et * 16 + lr];
    half8t br[4];
    if (lk < 16) {
      #pragma unroll
      for (int et = 0; et < 4; ++et) {
        float d = dA[et];
        #pragma unroll
        for (int i = 0; i < 8; ++i) {
          float dd = d - (float)(lk + i) * (5.0f / 15.0f);
          br[et][i] = (_Float16)__expf(-10.24f * dd * dd);
        }
      }
    } else {
      #pragma unroll
      for (int et = 0; et < 4; ++et)
        #pragma unroll
        for (int i = 0; i < 8; ++i) br[et][i] = (_Float16)0.0f;
    }
    half8t ar[2];
    #pragma unroll
    for (int cj = 0; cj < 2; ++cj)
      ar[cj] = *(const half8t*)&Wr[(((size_t)(ct0 + cj)) * 64 + l) * 8];
    #pragma unroll
    for (int et = 0; et < 4; ++et)
      #pragma unroll
      for (int cj = 0; cj < 2; ++cj)
        acc[cj][et] = __builtin_amdgcn_mfma_f32_16x16x32_f16(ar[cj], br[et], acc[cj][et], 0, 0, 0);
  }
  __syncthreads();   // all Psum reads done -> buffer reusable for M1

  // ---- phase 3: silu -> M1 (aliases Psum region) ----
  #pragma unroll
  for (int cj = 0; cj < 2; ++cj) {
    f32x4 b1v = *(const f32x4*)&be1[(ct0 + cj) * 16 + g4];
    #pragma unroll
    for (int et = 0; et < 4; ++et) {
      half4t m4;
      #pragma unroll
      for (int rr = 0; rr < 4; ++rr)
        m4[rr] = (_Float16)silu_f(acc[cj][et][rr] + b1v[rr]);
      *(half4t*)&SH[(et * 16 + lr) * ES + (ct0 + cj) * 16 + g4] = m4;
    }
  }
  __syncthreads();

  // ---- phase 4: mm2T: acc2 = We2^T @ M1^T ----
  f32x4 acc2[2][4] = {};
  #pragma unroll
  for (int kt = 0; kt < 4; ++kt) {
    half8t a2[2], b2[4];
    #pragma unroll
    for (int cj = 0; cj < 2; ++cj)
      a2[cj] = *(const half8t*)&W2p[(((size_t)kt * 8 + ct0 + cj) * 64 + l) * 8];
    #pragma unroll
    for (int et = 0; et < 4; ++et)
      b2[et] = *(const half8t*)&SH[(et * 16 + lr) * ES + kt * 32 + lk];
    #pragma unroll
    for (int cj = 0; cj < 2; ++cj)
      #pragma unroll
      for (int et = 0; et < 4; ++et)
        acc2[cj][et] = __builtin_amdgcn_mfma_f32_16x16x32_f16(a2[cj], b2[et], acc2[cj][et], 0, 0, 0);
  }
  __syncthreads();   // M1 reads done -> buffer reusable for M2h

  // ---- phase 5: silu -> M2h (fp16, aliases again) ----
  #pragma unroll
  for (int cj = 0; cj < 2; ++cj) {
    f32x4 b2v = *(const f32x4*)&be2[(ct0 + cj) * 16 + g4];
    #pragma unroll
    for (int et = 0; et < 4; ++et) {
      half4t m4;
      #pragma unroll
      for (int rr = 0; rr < 4; ++rr)
        m4[rr] = (_Float16)silu_f(acc2[cj][et][rr] + b2v[rr]);
      *(half4t*)&SH[(et * 16 + lr) * ES + (ct0 + cj) * 16 + g4] = m4;
    }
  }
  __syncthreads();

  // ---- phase 6: segmented reduce over dst runs ----
  {
    int cp = tid & 63, qr = tid >> 6;
    int rbeg = qr * 16, rend = rbeg + 16;
    float a0 = 0.f, a1 = 0.f;
    int prev = -1;
    for (int r = rbeg; r < rend; ++r) {
      int dv = dstv[r];
      half2t v = *(const half2t*)&SH[r * ES + cp * 2];
      if (dv != prev) {
        if (prev >= 0) {
          atomicAdd(&agg[(size_t)prev * H + cp * 2], a0);
          atomicAdd(&agg[(size_t)prev * H + cp * 2 + 1], a1);
        }
        a0 = a1 = 0.f;
        prev = dv;
      }
      if (dv >= 0) { a0 += (float)v[0]; a1 += (float)v[1]; }
    }
    if (prev >= 0) {
      atomicAdd(&agg[(size_t)prev * H + cp * 2], a0);
      atomicAdd(&agg[(size_t)prev * H + cp * 2 + 1], a1);
    }
  }
}

// ---------------- node MLP: fp16 MFMA, 32 atoms/block ----------------------
#define NXS 264   // X stride fp16 (528B)
#define M1S 136

__global__ __launch_bounds__(256) void k_node_mfma(
    float* __restrict__ h, unsigned short* __restrict__ hb,
    const float* __restrict__ agg,
    const unsigned short* __restrict__ W1p, const float* __restrict__ bh1,
    const unsigned short* __restrict__ W2p, const float* __restrict__ bh2, int A) {
  __shared__ __align__(16) unsigned short Xs[32 * NXS];   // 16896 B
  __shared__ __align__(16) unsigned short Us[32 * M1S];   //  8704 B
  const int tid = threadIdx.x;
  const int a0 = blockIdx.x * 32;
  {
    const int r = tid >> 3, oct = tid & 7;   // 8 threads per atom row
    int a = a0 + r; if (a >= A) a = A - 1;
    const u16x8* hr = (const u16x8*)(hb + (size_t)a * H);
    u16x8* xr = (u16x8*)&Xs[r * NXS];
    xr[oct * 2]     = hr[oct * 2];
    xr[oct * 2 + 1] = hr[oct * 2 + 1];
    const float4* ar = (const float4*)(agg + (size_t)a * H);
    u16x8 tmp[2];
    unsigned short* tp = (unsigned short*)tmp;
    #pragma unroll
    for (int i = 0; i < 4; ++i) {
      float4 av = ar[oct * 4 + i];
      tp[i*4+0] = f16u(av.x); tp[i*4+1] = f16u(av.y);
      tp[i*4+2] = f16u(av.z); tp[i*4+3] = f16u(av.w);
    }
    xr[16 + oct * 2]     = tmp[0];
    xr[16 + oct * 2 + 1] = tmp[1];
  }
  __syncthreads();

  const int l = tid & 63, wv = tid >> 6;
  const int lr = l & 15, lk = (l >> 4) * 8;
  const int ct0 = wv * 2;
  const int c0 = ct0 * 16 + lr, c1 = c0 + 16;
  const float b1a = bh1[c0], b1b = bh1[c1];
  const float b2a = bh2[c0], b2b = bh2[c1];

  f32x4 acc[2][2] = {};
  #pragma unroll
  for (int kt = 0; kt < 8; ++kt) {
    half8t a[2], b[2];
    #pragma unroll
    for (int rt = 0; rt < 2; ++rt)
      a[rt] = *(const half8t*)&Xs[(rt * 16 + lr) * NXS + kt * 32 + lk];
    #pragma unroll
    for (int j = 0; j < 2; ++j)
      b[j] = *(const half8t*)&W1p[(((size_t)kt * 8 + ct0 + j) * 64 + l) * 8];
    #pragma unroll
    for (int rt = 0; rt < 2; ++rt)
      #pragma unroll
      for (int j = 0; j < 2; ++j)
        acc[rt][j] = __builtin_amdgcn_mfma_f32_16x16x32_f16(a[rt], b[j], acc[rt][j], 0, 0, 0);
  }
  #pragma unroll
  for (int rt = 0; rt < 2; ++rt)
    #pragma unroll
    for (int j = 0; j < 2; ++j) {
      float bb = j ? b1b : b1a;
      int col = (ct0 + j) * 16 + lr;
      #pragma unroll
      for (int rr = 0; rr < 4; ++rr) {
        int row = rt * 16 + (l >> 4) * 4 + rr;
        Us[row * M1S + col] = f16u(silu_f(acc[rt][j][rr] + bb));
      }
    }
  __syncthreads();

  f32x4 acc2[2][2] = {};
  #pragma unroll
  for (int kt = 0; kt < 4; ++kt) {
    half8t a[2], b[2];
    #pragma unroll
    for (int rt = 0; rt < 2; ++rt)
      a[rt] = *(const half8t*)&Us[(rt * 16 + lr) * M1S + kt * 32 + lk];
    #pragma unroll
    for (int j = 0; j < 2; ++j)
      b[j] = *(const half8t*)&W2p[(((size_t)kt * 8 + ct0 + j) * 64 + l) * 8];
    #pragma unroll
    for (int rt = 0; rt < 2; ++rt)
      #pragma unroll
      for (int j = 0; j < 2; ++j)
        acc2[rt][j] = __builtin_amdgcn_mfma_f32_16x16x32_f16(a[rt], b[j], acc2[rt][j], 0, 0, 0);
  }
  #pragma unroll
  for (int rt = 0; rt < 2; ++rt)
    #pragma unroll
    for (int j = 0; j < 2; ++j) {
      float bb = j ? b2b : b2a;
      int col = (ct0 + j) * 16 + lr;
      #pragma unroll
      for (int rr = 0; rr < 4; ++rr) {
        int row = rt * 16 + (l >> 4) * 4 + rr;
        int a = a0 + row;
        if (a < A) {
          size_t off = (size_t)a * H + col;
          float nh = h[off] + acc2[rt][j][rr] + bb;
          h[off] = nh;
          hb[off] = f16u(nh);
        }
      }
    }
}

// ---------------- tail kernels ---------------------------------------------
__global__ void k_q4(const float* __restrict__ residue_embed,
                     const float* __restrict__ Wq, const float* __restrict__ bq,
                     float* __restrict__ q4) {
  int i = blockIdx.x * blockDim.x + threadIdx.x;
  if (i >= 4 * H) return;
  int r = i >> 7, j = i & 127;
  const float* emb = residue_embed + (size_t)r * H;
  float s = bq[j];
  #pragma unroll 4
  for (int k = 0; k < H; ++k) s += emb[k] * Wq[(size_t)k*H + j];
  q4[i] = s;
}

// per-residue attention pooling over fp16 kv rows [k(128) | v(128)]
__global__ __launch_bounds__(256) void k_pool(
    const float* __restrict__ q4, const int* __restrict__ rtype,
    const unsigned short* __restrict__ kv, const int* __restrict__ starts,
    const int* __restrict__ apr, float* __restrict__ pooled, int N) {
  int r = blockIdx.x * 4 + (threadIdx.x >> 6);
  if (r >= N) return;
  int lane = threadIdx.x & 63;
  int s0 = starts[r], cnt = apr[r];
  const float* qrow = q4 + (size_t)rtype[r] * H;
  float q0 = qrow[lane], q1 = qrow[64 + lane];
  float myscore = -1e30f;
  for (int i = 0; i < cnt; ++i) {
    const unsigned short* kr = kv + (size_t)(s0 + i) * 256;
    float p = q0 * (float)(*(const _Float16*)&kr[lane]) +
              q1 * (float)(*(const _Float16*)&kr[64 + lane]);
    #pragma unroll
    for (int off = 32; off; off >>= 1) p += __shfl_xor(p, off);
    if (lane == i) myscore = p * 0.08838834764831845f;
  }
  float val = (lane < cnt) ? myscore : -1e30f;
  float mx = val;
  #pragma unroll
  for (int off = 32; off; off >>= 1) mx = fmaxf(mx, __shfl_xor(mx, off));
  float ex = (lane < cnt) ? __expf(val - mx) : 0.0f;
  float sum = ex;
  #pragma unroll
  for (int off = 32; off; off >>= 1) sum += __shfl_xor(sum, off);
  float w = ex * __builtin_amdgcn_rcpf(sum);
  float p0 = 0.f, p1 = 0.f;
  for (int i = 0; i < cnt; ++i) {
    float wi = __shfl(w, i);
    const unsigned short* vr = kv + (size_t)(s0 + i) * 256 + 128;
    p0 += wi * (float)(*(const _Float16*)&vr[lane]);
    p1 += wi * (float)(*(const _Float16*)&vr[64 + lane]);
  }
  pooled[(size_t)r*H + lane] = p0;
  pooled[(size_t)r*H + 64 + lane] = p1;
}

__global__ void k_head(const float* __restrict__ pooled,
                       const float* __restrict__ Wmu, const float* __restrict__ bmu,
                       const float* __restrict__ Wlv, const float* __restrict__ blv,
                       float* __restrict__ out, int N) {
  int i = blockIdx.x * blockDim.x + threadIdx.x;
  if (i >= N * LATD) return;
  int r = i >> 5, j = i & 31;
  const float* p = pooled + (size_t)r * H;
  float smu = 0.f, slv = 0.f;
  #pragma unroll 4
  for (int k = 0; k < H; ++k) {
    float pv = p[k];
    smu += pv * Wmu[(size_t)k*LATD + j];
    slv += pv * Wlv[(size_t)k*LATD + j];
  }
  smu += bmu[j];
  slv += blv[j];
  slv = fminf(fmaxf(slv, -10.0f), 2.0f);
  out[i] = smu;
  out[(size_t)N*LATD + i] = slv;
}

extern "C" void kernel_launch(void* const* d_in, const int* in_sizes, int n_in,
                              void* d_out, int out_size, void* d_ws, size_t ws_size,
                              hipStream_t stream) {
  const float* coords        = (const float*)d_in[0];
  const int*   atype         = (const int*)d_in[1];
  const int*   ridx          = (const int*)d_in[2];
  const int*   rtype         = (const int*)d_in[3];
  const int*   apr           = (const int*)d_in[4];
  const int*   esrc          = (const int*)d_in[5];
  const int*   edst          = (const int*)d_in[6];
  const float* atom_embed    = (const float*)d_in[7];
  const float* residue_embed = (const float*)d_in[8];
  const float* We1 = (const float*)d_in[9];
  const float* be1 = (const float*)d_in[10];
  const float* We2 = (const float*)d_in[11];
  const float* be2 = (const float*)d_in[12];
  const float* Wh1 = (const float*)d_in[13];
  const float* bh1 = (const float*)d_in[14];
  const float* Wh2 = (const float*)d_in[15];
  const float* bh2 = (const float*)d_in[16];
  const float* Wq  = (const float*)d_in[17];
  const float* bq  = (const float*)d_in[18];
  const float* Wk  = (const float*)d_in[19];
  const float* bk  = (const float*)d_in[20];
  const float* Wv  = (const float*)d_in[21];
  const float* bv  = (const float*)d_in[22];
  const float* Wmu = (const float*)d_in[23];
  const float* bmu = (const float*)d_in[24];
  const float* Wlv = (const float*)d_in[25];
  const float* blv = (const float*)d_in[26];

  const int A = in_sizes[1];
  const int N = in_sizes[3];
  const int E = in_sizes[5];

  float* ws     = (float*)d_ws;
  float* h      = ws;                              // A*H f32
  float* agg    = h + (size_t)A * H;               // A*H f32
  float* vbuf   = agg + (size_t)A * H;             // A*H f32 (aliased: Ph, then kv)
  float* dbuf   = vbuf + (size_t)A * H;            // E f32
  float* q4     = dbuf + (size_t)E;                // 4*H
  float* bkv    = q4 + 4 * H;                      // 256
  float* pooled = bkv + 256;                       // N*H
  int*   starts = (int*)(pooled + (size_t)N * H);  // N
  unsigned short* hbuf = (unsigned short*)(starts + N);  // A*H fp16
  int*   eperm  = (int*)(hbuf + (size_t)A * H);    // E
  int*   cnt    = eperm + (size_t)E;               // A
  int*   cursor = cnt + A;                         // A
  int*   bsum   = cursor + A;                      // 64
  unsigned short* wp = (unsigned short*)(bsum + 64);     // WP_TOTAL fp16
  unsigned short* Ph = (unsigned short*)vbuf;      // A*256 fp16 == A*H f32 bytes

  k_init_h<<<(A * H + 255) / 256, 256, 0, stream>>>(atom_embed, residue_embed,
                                                    atype, ridx, rtype, h, hbuf, A);
  k_dist<<<(E + 255) / 256, 256, 0, stream>>>(coords, esrc, edst, dbuf, E);
  k_starts<<<(A + 255) / 256, 256, 0, stream>>>(ridx, starts, A);
  k_pack<<<(WP_TOTAL + 255) / 256, 256, 0, stream>>>(We1, We2, Wh1, Wh2, Wk, Wv, wp);
  k_bias2<<<1, 256, 0, stream>>>(bk, bv, bkv);

  // counting sort of edges by dst (two-level scan)
  const int nb = (A + 1023) / 1024;
  hipMemsetAsync(cnt, 0, (size_t)A * sizeof(int), stream);
  k_hist<<<(E + 255) / 256, 256, 0, stream>>>(edst, cnt, E);
  k_scanA<<<nb, 1024, 0, stream>>>(cnt, cursor, bsum, A);
  k_scanB<<<1, 64, 0, stream>>>(bsum, nb);
  k_scanC<<<(A + 255) / 256, 256, 0, stream>>>(cursor, bsum, A);
  k_scatter<<<(E + 255) / 256, 256, 0, stream>>>(edst, cursor, eperm, E);

  for (int l = 0; l < 3; ++l) {
    hipMemsetAsync(agg, 0, (size_t)A * H * sizeof(float), stream);
    k_proj<<<(A + 63) / 64, 256, 0, stream>>>(
        hbuf, wp + OFF_PROJ + (size_t)l * 32768, Ph, A, nullptr);
    k_edge_mfma<<<(E + 63) / 64, 256, 0, stream>>>(
        Ph, dbuf, esrc, edst, eperm,
        wp + OFF_RBF + (size_t)l * 4096,  be1 + (size_t)l * H,
        wp + OFF_W2  + (size_t)l * 16384, be2 + (size_t)l * H, agg, E);
    k_node_mfma<<<(A + 31) / 32, 256, 0, stream>>>(
        h, hbuf, agg,
        wp + OFF_H1 + (size_t)l * 32768, bh1 + (size_t)l * H,
        wp + OFF_H2 + (size_t)l * 16384, bh2 + (size_t)l * H, A);
  }

  k_q4<<<2, 256, 0, stream>>>(residue_embed, Wq, bq, q4);
  unsigned short* kv = Ph;  // Ph dead after last edge; reuse A*256 fp16 region
  k_proj<<<(A + 63) / 64, 256, 0, stream>>>(hbuf, wp + OFF_KV, kv, A, bkv);
  k_pool<<<(N + 3) / 4, 256, 0, stream>>>(q4, rtype, kv, starts, apr, pooled, N);
  k_head<<<(N * LATD + 255) / 256, 256, 0, stream>>>(pooled, Wmu, bmu, Wlv, blv,
                                                     (float*)d_out, N);
}